// Round 2
// baseline (901.308 us; speedup 1.0000x reference)
//
#include <hip/hip_runtime.h>

#define B_ 2
#define H_ 16
#define S_ 2048
#define D_ 64
#define QB 32
#define KT 64
#define NKT (S_ / KT)   // 32
#define NT 512

typedef _Float16 f16;
typedef _Float16 f16x8 __attribute__((ext_vector_type(8)));
typedef _Float16 f16x4 __attribute__((ext_vector_type(4)));
typedef _Float16 f16x2 __attribute__((ext_vector_type(2)));
typedef float f32x4 __attribute__((ext_vector_type(4)));

#define MFMA16(a, b, c) __builtin_amdgcn_mfma_f32_16x16x32_f16(a, b, c, 0, 0, 0)

// LDS row strides (f16 elements). KS/QS/PS: 144B rows (16B-aligned for b128).
// VS = 66 -> 33-dword (odd) rows: scalar u16 column reads are conflict-free.
#define KS 72
#define VS 66
#define PS 72
#define QS 72

__global__ __launch_bounds__(NT, 4)
void attn_kernel(const float* __restrict__ q, const float* __restrict__ k,
                 const float* __restrict__ v, const int* __restrict__ mask,
                 float* __restrict__ out)
{
    __shared__ __align__(16) f16 Qsh[QB][QS];        // 4.6 KB
    __shared__ __align__(16) f16 Ksh[2][KT][KS];     // 18.4 KB (double buf)
    __shared__ __align__(16) f16 Vsh[3][KT][VS];     // 25.3 KB (triple buf)
    __shared__ __align__(16) f16 Psh[2][QB][PS];     // 9.2 KB (double buf)
    __shared__ float rowred[QB];
    __shared__ float rlsh[QB];

    const int tid  = threadIdx.x;
    const int wave = tid >> 6;
    const int lane = tid & 63;
    const int quad = lane >> 4;
    const int l16  = lane & 15;
    const int qi   = wave & 1;   // q 16-row half
    const int ni   = wave >> 1;  // score-col / O d-col 16-block

    const int qb = blockIdx.x;
    const int h  = blockIdx.y;
    const int b  = blockIdx.z;
    const int bh = b * H_ + h;

    const float* Qg = q + ((size_t)bh * S_ + (size_t)qb * QB) * D_;
    const float* Kg = k + (size_t)bh * S_ * D_;
    const float* Vg = v + (size_t)bh * S_ * D_;
    const int*   Mg = mask + ((size_t)b * S_ + (size_t)qb * QB) * S_;
    float* res_out  = out + ((size_t)bh * S_ + (size_t)qb * QB) * D_;
    float* attn_out = out + (size_t)B_ * H_ * S_ * D_
                          + ((size_t)bh * S_ + (size_t)qb * QB) * S_;

    if (tid < QB) rowred[tid] = 0.f;

    const int skk = tid >> 3;        // staging row (0..63)
    const int sd0 = (tid & 7) * 8;   // staging d-col

    // ---- stage Q (scale 1/8 folded in; exact in fp16) ----
    {
        const int row = tid >> 4;
        const int c4  = (tid & 15) * 4;
        const float4 qv = *(const float4*)(Qg + row * D_ + c4);
        f16x4 o;
        o[0] = (f16)(qv.x * 0.125f); o[1] = (f16)(qv.y * 0.125f);
        o[2] = (f16)(qv.z * 0.125f); o[3] = (f16)(qv.w * 0.125f);
        *(f16x4*)&Qsh[row][c4] = o;
    }

    // ---- stage K/V tile 0 ----
    {
        const float* sk = Kg + (size_t)skk * D_ + sd0;
        const float4 x0 = *(const float4*)sk, x1 = *(const float4*)(sk + 4);
        const float* sv = Vg + (size_t)skk * D_ + sd0;
        const float4 y0 = *(const float4*)sv, y1 = *(const float4*)(sv + 4);
        f16x8 ko;
        ko[0] = (f16)x0.x; ko[1] = (f16)x0.y; ko[2] = (f16)x0.z; ko[3] = (f16)x0.w;
        ko[4] = (f16)x1.x; ko[5] = (f16)x1.y; ko[6] = (f16)x1.z; ko[7] = (f16)x1.w;
        *(f16x8*)&Ksh[0][skk][sd0] = ko;
        f16x2 p0, p1, p2, p3;
        p0[0] = (f16)y0.x; p0[1] = (f16)y0.y;
        p1[0] = (f16)y0.z; p1[1] = (f16)y0.w;
        p2[0] = (f16)y1.x; p2[1] = (f16)y1.y;
        p3[0] = (f16)y1.z; p3[1] = (f16)y1.w;
        *(f16x2*)&Vsh[0][skk][sd0]     = p0;
        *(f16x2*)&Vsh[0][skk][sd0 + 2] = p1;
        *(f16x2*)&Vsh[0][skk][sd0 + 4] = p2;
        *(f16x2*)&Vsh[0][skk][sd0 + 6] = p3;
    }
    __syncthreads();

    const int qrow0 = qi * 16 + quad * 4;
    const f16x8 a0 = *(const f16x8*)&Qsh[qi * 16 + l16][quad * 8];
    const f16x8 a1 = *(const f16x8*)&Qsh[qi * 16 + l16][32 + quad * 8];

    const int colbase = ni * 16 + l16;
    const int* mp0 = Mg + (size_t)qrow0 * S_ + colbase;

    int mcur[4];
#pragma unroll
    for (int r = 0; r < 4; ++r) mcur[r] = mp0[(size_t)r * S_];

    float psum[4] = {0.f, 0.f, 0.f, 0.f};
    f32x4 oacc = {0.f, 0.f, 0.f, 0.f};
    f16x4 ereg[NKT];   // unnormalized exp(s), fp16, held in VGPRs

    // ================= single fused sweep: 1 barrier / iteration =================
#pragma unroll
    for (int kt = 0; kt < NKT; ++kt) {
        const int cur  = kt & 1, nxt = cur ^ 1;
        const int vcur = kt % 3, vnxt = (kt + 1) % 3;

        // prefetch next K/V/mask into registers (overlaps with MFMA below)
        float4 kx0, kx1, vx0, vx1;
        int mn[4];
        if (kt < NKT - 1) {
            const float* sk = Kg + (size_t)((kt + 1) * KT + skk) * D_ + sd0;
            kx0 = *(const float4*)sk; kx1 = *(const float4*)(sk + 4);
            const float* sv = Vg + (size_t)((kt + 1) * KT + skk) * D_ + sd0;
            vx0 = *(const float4*)sv; vx1 = *(const float4*)(sv + 4);
            const int* mp = mp0 + (kt + 1) * KT;
#pragma unroll
            for (int r = 0; r < 4; ++r) mn[r] = mp[(size_t)r * S_];
        }

        // QK^T on current K buffer
        const f16x8 b0 = *(const f16x8*)&Ksh[cur][ni * 16 + l16][quad * 8];
        const f16x8 b1 = *(const f16x8*)&Ksh[cur][ni * 16 + l16][32 + quad * 8];
        f32x4 c = {0.f, 0.f, 0.f, 0.f};
        c = MFMA16(a0, b0, c);
        c = MFMA16(a1, b1, c);

        // mask + exp (mask was prefetched last iteration)
        f16x4 ev;
#pragma unroll
        for (int r = 0; r < 4; ++r) {
            const float e = (mcur[r] == 1) ? 0.f : __expf(c[r]);
            psum[r] += e;
            ev[r] = (f16)e;
        }
        ereg[kt] = ev;
#pragma unroll
        for (int r = 0; r < 4; ++r) Psh[cur][qrow0 + r][colbase] = ev[r];

        // stage next K/V into the other buffers
        if (kt < NKT - 1) {
            f16x8 ko;
            ko[0] = (f16)kx0.x; ko[1] = (f16)kx0.y; ko[2] = (f16)kx0.z; ko[3] = (f16)kx0.w;
            ko[4] = (f16)kx1.x; ko[5] = (f16)kx1.y; ko[6] = (f16)kx1.z; ko[7] = (f16)kx1.w;
            *(f16x8*)&Ksh[nxt][skk][sd0] = ko;
            f16x2 p0, p1, p2, p3;
            p0[0] = (f16)vx0.x; p0[1] = (f16)vx0.y;
            p1[0] = (f16)vx0.z; p1[1] = (f16)vx0.w;
            p2[0] = (f16)vx1.x; p2[1] = (f16)vx1.y;
            p3[0] = (f16)vx1.z; p3[1] = (f16)vx1.w;
            *(f16x2*)&Vsh[vnxt][skk][sd0]     = p0;
            *(f16x2*)&Vsh[vnxt][skk][sd0 + 2] = p1;
            *(f16x2*)&Vsh[vnxt][skk][sd0 + 4] = p2;
            *(f16x2*)&Vsh[vnxt][skk][sd0 + 6] = p3;
#pragma unroll
            for (int r = 0; r < 4; ++r) mcur[r] = mn[r];
        }

        __syncthreads();

        // PV on current P/V buffers (raw e; 1/l applied at the end)
        const f16x8 pa0 = *(const f16x8*)&Psh[cur][qi * 16 + l16][quad * 8];
        const f16x8 pa1 = *(const f16x8*)&Psh[cur][qi * 16 + l16][32 + quad * 8];
        f16x8 vb0, vb1;
        const int dcol = ni * 16 + l16;
#pragma unroll
        for (int j = 0; j < 8; ++j) {
            vb0[j] = Vsh[vcur][quad * 8 + j][dcol];
            vb1[j] = Vsh[vcur][32 + quad * 8 + j][dcol];
        }
        oacc = MFMA16(pa0, vb0, oacc);
        oacc = MFMA16(pa1, vb1, oacc);
    }

    // ---- row-sum reduction -> 1/l ----
#pragma unroll
    for (int r = 0; r < 4; ++r) {
        psum[r] += __shfl_xor(psum[r], 1);
        psum[r] += __shfl_xor(psum[r], 2);
        psum[r] += __shfl_xor(psum[r], 4);
        psum[r] += __shfl_xor(psum[r], 8);
    }
    if (l16 == 0) {
#pragma unroll
        for (int r = 0; r < 4; ++r) atomicAdd(&rowred[qrow0 + r], psum[r]);
    }
    __syncthreads();
    if (tid < QB) rlsh[tid] = 1.0f / rowred[tid];
    __syncthreads();
    float rlq[4];
#pragma unroll
    for (int r = 0; r < 4; ++r) rlq[r] = rlsh[qrow0 + r];

    // ---- barrier-free streaming epilogue: attn stores (537 MB total) ----
    float* ap0 = attn_out + (size_t)qrow0 * S_ + colbase;
#pragma unroll
    for (int kt = 0; kt < NKT; ++kt) {
#pragma unroll
        for (int r = 0; r < 4; ++r)
            ap0[(size_t)r * S_ + kt * KT] = (float)ereg[kt][r] * rlq[r];
    }

    // ---- res ----
#pragma unroll
    for (int r = 0; r < 4; ++r)
        res_out[(size_t)(qrow0 + r) * D_ + ni * 16 + l16] = oacc[r] * rlq[r];
}

extern "C" void kernel_launch(void* const* d_in, const int* in_sizes, int n_in,
                              void* d_out, int out_size, void* d_ws, size_t ws_size,
                              hipStream_t stream) {
    (void)in_sizes; (void)n_in; (void)out_size; (void)d_ws; (void)ws_size;
    const float* q   = (const float*)d_in[0];
    const float* k   = (const float*)d_in[1];
    const float* v   = (const float*)d_in[2];
    const int*  mask = (const int*)d_in[3];
    float* out = (float*)d_out;
    dim3 grid(S_ / QB, H_, B_);   // qblock fastest -> K/V L2 reuse
    attn_kernel<<<grid, dim3(NT), 0, stream>>>(q, k, v, mask, out);
}